// Round 4
// baseline (39.835 us; speedup 1.0000x reference)
//
#include <hip/hip_runtime.h>

// Problem constants (B, L, D from reference)
#define BB 64
#define LL 4096
#define DD 256
#define PP 64              // chunks per batch; rows per chunk = LL/PP = 64
#define ROWS_PER_CHUNK (LL / PP)
#define D4 (DD / 4)        // float4 per row = 64
#define WAVES 4            // waves per block, phase 1
#define RWAVES 8           // waves per block, phase 2

// ---------------- Phase 1: per-(batch, chunk) partial sums ----------------
// TRANSPOSED mapping: c = block*4 + w; b = c % 64 (fast axis), p = c / 64.
// -> every CU gets a uniform mix of low-p (always active) and high-p (rarely
//    active) chunks, equalizing per-CU active-wave count.
// Full chunks take a fixed-count 64-iter loop unrolled x8 (8 loads in flight
// per lane = 8 KiB/wave) with two accumulators.
__global__ __launch_bounds__(256) void avg_partial_kernel(
    const float* __restrict__ in,        // [B, L, D]
    const int* __restrict__ len,         // [B] (int32)
    float* __restrict__ ws)              // [B, PP, D]
{
    const int w    = threadIdx.x >> 6;
    const int lane = threadIdx.x & 63;
    const int c    = blockIdx.x * WAVES + w;
    const int b    = c & (BB - 1);       // batch  (fast)
    const int p    = c >> 6;             // chunk  (slow)

    const int lb   = len[b];
    const int row0 = p << 6;             // p * 64
    if (row0 >= lb) return;              // inactive chunk: never written, never read

    const float4* __restrict__ base =
        (const float4*)(in + (size_t)b * LL * DD) + (size_t)row0 * D4 + lane;

    int n = lb - row0;
    if (n > ROWS_PER_CHUNK) n = ROWS_PER_CHUNK;

    float4 a0 = make_float4(0.f, 0.f, 0.f, 0.f);
    float4 a1 = make_float4(0.f, 0.f, 0.f, 0.f);

    if (n == ROWS_PER_CHUNK) {
        // full chunk: compile-time trip count, deep MLP
        #pragma unroll
        for (int r = 0; r < ROWS_PER_CHUNK; r += 8) {
            float4 v0 = base[(size_t)(r + 0) * D4];
            float4 v1 = base[(size_t)(r + 1) * D4];
            float4 v2 = base[(size_t)(r + 2) * D4];
            float4 v3 = base[(size_t)(r + 3) * D4];
            float4 v4 = base[(size_t)(r + 4) * D4];
            float4 v5 = base[(size_t)(r + 5) * D4];
            float4 v6 = base[(size_t)(r + 6) * D4];
            float4 v7 = base[(size_t)(r + 7) * D4];
            a0.x += v0.x + v2.x + v4.x + v6.x;  a1.x += v1.x + v3.x + v5.x + v7.x;
            a0.y += v0.y + v2.y + v4.y + v6.y;  a1.y += v1.y + v3.y + v5.y + v7.y;
            a0.z += v0.z + v2.z + v4.z + v6.z;  a1.z += v1.z + v3.z + v5.z + v7.z;
            a0.w += v0.w + v2.w + v4.w + v6.w;  a1.w += v1.w + v3.w + v5.w + v7.w;
        }
    } else {
        for (int r = 0; r < n; ++r) {
            float4 v = base[(size_t)r * D4];
            a0.x += v.x; a0.y += v.y; a0.z += v.z; a0.w += v.w;
        }
    }

    float4 acc = make_float4(a0.x + a1.x, a0.y + a1.y, a0.z + a1.z, a0.w + a1.w);
    float4* __restrict__ wsb = (float4*)ws + ((size_t)b * PP + p) * D4;
    wsb[lane] = acc;
}

// ---------------- Phase 2: reduce active partials, divide by length ----------------
// 64 blocks x 512 threads (8 waves). Wave w sums partials p = w, w+8, ...
// (active only), LDS combine, wave 0 writes out.
__global__ __launch_bounds__(512) void avg_reduce_kernel(
    const float* __restrict__ ws,        // [B, PP, D]
    const int* __restrict__ len,         // [B]
    float* __restrict__ out)             // [B, D]
{
    const int b    = blockIdx.x;
    const int w    = threadIdx.x >> 6;
    const int lane = threadIdx.x & 63;

    int lb = len[b];
    if (lb < 1) lb = 1;
    const int nchunks = (lb + ROWS_PER_CHUNK - 1) >> 6;

    float4 acc = make_float4(0.f, 0.f, 0.f, 0.f);
    const float4* __restrict__ wsb = (const float4*)ws + (size_t)b * PP * D4;

    #pragma unroll 2
    for (int p = w; p < nchunks; p += RWAVES) {
        float4 v = wsb[(size_t)p * D4 + lane];
        acc.x += v.x; acc.y += v.y; acc.z += v.z; acc.w += v.w;
    }

    __shared__ float4 sh[RWAVES - 1][64];
    if (w > 0) sh[w - 1][lane] = acc;
    __syncthreads();

    if (w == 0) {
        #pragma unroll
        for (int i = 0; i < RWAVES - 1; ++i) {
            float4 v = sh[i][lane];
            acc.x += v.x; acc.y += v.y; acc.z += v.z; acc.w += v.w;
        }
        const float inv = 1.0f / (float)lb;
        float4 o = make_float4(acc.x * inv, acc.y * inv, acc.z * inv, acc.w * inv);
        ((float4*)out)[(size_t)b * D4 + lane] = o;
    }
}

// ---------------- Fallback (tiny ws): zero-out + atomic accumulate ----------------
__global__ void avg_zero_out_kernel(float* __restrict__ out) {
    int i = blockIdx.x * blockDim.x + threadIdx.x;
    if (i < BB * DD) out[i] = 0.f;
}

__global__ __launch_bounds__(64) void avg_atomic_kernel(
    const float* __restrict__ in,
    const int* __restrict__ len,
    float* __restrict__ out)
{
    const int b    = blockIdx.x / PP;
    const int p    = blockIdx.x % PP;
    const int lane = threadIdx.x;

    int lb = len[b];
    if (lb < 1) lb = 1;
    const int row0 = p * ROWS_PER_CHUNK;
    int rend = row0 + ROWS_PER_CHUNK;
    if (rend > lb) rend = (lb > row0) ? lb : row0;
    if (rend <= row0) return;

    float4 acc = make_float4(0.f, 0.f, 0.f, 0.f);
    const float4* __restrict__ base = (const float4*)(in + (size_t)b * LL * DD);
    for (int r = row0; r < rend; ++r) {
        float4 v = base[(size_t)r * D4 + lane];
        acc.x += v.x; acc.y += v.y; acc.z += v.z; acc.w += v.w;
    }
    const float inv = 1.0f / (float)lb;
    float* o = out + (size_t)b * DD + lane * 4;
    atomicAdd(o + 0, acc.x * inv);
    atomicAdd(o + 1, acc.y * inv);
    atomicAdd(o + 2, acc.z * inv);
    atomicAdd(o + 3, acc.w * inv);
}

extern "C" void kernel_launch(void* const* d_in, const int* in_sizes, int n_in,
                              void* d_out, int out_size, void* d_ws, size_t ws_size,
                              hipStream_t stream) {
    const float* in  = (const float*)d_in[0];
    const int*   len = (const int*)d_in[1];
    float*       out = (float*)d_out;

    const size_t ws_needed = (size_t)BB * PP * DD * sizeof(float); // 4 MiB

    if (ws_size >= ws_needed && d_ws != nullptr) {
        float* ws = (float*)d_ws;
        avg_partial_kernel<<<(BB * PP) / WAVES, 256, 0, stream>>>(in, len, ws);
        avg_reduce_kernel<<<BB, 512, 0, stream>>>(ws, len, out);
    } else {
        avg_zero_out_kernel<<<(BB * DD + 255) / 256, 256, 0, stream>>>(out);
        avg_atomic_kernel<<<BB * PP, 64, 0, stream>>>(in, len, out);
    }
}

// Round 5
// 30.460 us; speedup vs baseline: 1.3078x; 1.3078x over previous
//
#include <hip/hip_runtime.h>

// Problem constants (B, L, D from reference)
#define BB 64
#define LL 4096
#define DD 256
#define D4 (DD / 4)        // float4 per row = 64
#define WAVES 4            // waves per block, phase 1
#define RWAVES 8           // waves per block, phase 2

// ---------------- Phase 1: per-(batch, chunk) partial sums ----------------
// b-major mapping (R3, proven): c = block*4 + w; b = c / PP, p = c % PP.
// Runtime-trip loop with unroll 8 -> max 8 loads in flight per lane, no spill.
// PP=128 (32-row chunks) => 2048 blocks = 8 blocks/CU = 32 waves/CU (max TLP).
template <int PP>
__global__ __launch_bounds__(256) void avg_partial_kernel(
    const float* __restrict__ in,        // [B, L, D]
    const int* __restrict__ len,         // [B] (int32)
    float* __restrict__ ws)              // [B, PP, D]
{
    constexpr int RPC = LL / PP;         // rows per chunk
    const int w    = threadIdx.x >> 6;
    const int lane = threadIdx.x & 63;
    const int c    = blockIdx.x * WAVES + w;
    const int b    = c / PP;             // batch (slow axis)
    const int p    = c % PP;             // chunk (fast axis) — PP is pow2

    const int lb   = len[b];
    const int row0 = p * RPC;
    if (row0 >= lb) return;              // inactive: never written, never read

    int n = lb - row0;
    if (n > RPC) n = RPC;

    const float4* __restrict__ base =
        (const float4*)(in + (size_t)b * LL * DD) + (size_t)row0 * D4 + lane;

    float4 acc = make_float4(0.f, 0.f, 0.f, 0.f);
    #pragma unroll 8
    for (int r = 0; r < n; ++r) {
        float4 v = base[(size_t)r * D4];
        acc.x += v.x; acc.y += v.y; acc.z += v.z; acc.w += v.w;
    }

    float4* __restrict__ wsb = (float4*)ws + ((size_t)b * PP + p) * D4;
    wsb[lane] = acc;
}

// ---------------- Phase 2: reduce active partials, divide by length ----------------
// 64 blocks x 512 threads (8 waves). Wave w sums partials p = w, w+8, ...
// (active only), LDS combine, wave 0 writes out.
template <int PP>
__global__ __launch_bounds__(512) void avg_reduce_kernel(
    const float* __restrict__ ws,        // [B, PP, D]
    const int* __restrict__ len,         // [B]
    float* __restrict__ out)             // [B, D]
{
    constexpr int RPC = LL / PP;
    const int b    = blockIdx.x;
    const int w    = threadIdx.x >> 6;
    const int lane = threadIdx.x & 63;

    int lb = len[b];
    if (lb < 1) lb = 1;
    const int nchunks = (lb + RPC - 1) / RPC;

    float4 acc = make_float4(0.f, 0.f, 0.f, 0.f);
    const float4* __restrict__ wsb = (const float4*)ws + (size_t)b * PP * D4;

    #pragma unroll 4
    for (int p = w; p < nchunks; p += RWAVES) {
        float4 v = wsb[(size_t)p * D4 + lane];
        acc.x += v.x; acc.y += v.y; acc.z += v.z; acc.w += v.w;
    }

    __shared__ float4 sh[RWAVES - 1][64];
    if (w > 0) sh[w - 1][lane] = acc;
    __syncthreads();

    if (w == 0) {
        #pragma unroll
        for (int i = 0; i < RWAVES - 1; ++i) {
            float4 v = sh[i][lane];
            acc.x += v.x; acc.y += v.y; acc.z += v.z; acc.w += v.w;
        }
        const float inv = 1.0f / (float)lb;
        float4 o = make_float4(acc.x * inv, acc.y * inv, acc.z * inv, acc.w * inv);
        ((float4*)out)[(size_t)b * D4 + lane] = o;
    }
}

// ---------------- Fallback (tiny ws): zero-out + atomic accumulate ----------------
__global__ void avg_zero_out_kernel(float* __restrict__ out) {
    int i = blockIdx.x * blockDim.x + threadIdx.x;
    if (i < BB * DD) out[i] = 0.f;
}

__global__ __launch_bounds__(64) void avg_atomic_kernel(
    const float* __restrict__ in,
    const int* __restrict__ len,
    float* __restrict__ out)
{
    const int b    = blockIdx.x >> 6;
    const int p    = blockIdx.x & 63;
    const int lane = threadIdx.x;

    int lb = len[b];
    if (lb < 1) lb = 1;
    const int row0 = p * 64;
    int rend = row0 + 64;
    if (rend > lb) rend = (lb > row0) ? lb : row0;
    if (rend <= row0) return;

    float4 acc = make_float4(0.f, 0.f, 0.f, 0.f);
    const float4* __restrict__ base = (const float4*)(in + (size_t)b * LL * DD);
    for (int r = row0; r < rend; ++r) {
        float4 v = base[(size_t)r * D4 + lane];
        acc.x += v.x; acc.y += v.y; acc.z += v.z; acc.w += v.w;
    }
    const float inv = 1.0f / (float)lb;
    float* o = out + (size_t)b * DD + lane * 4;
    atomicAdd(o + 0, acc.x * inv);
    atomicAdd(o + 1, acc.y * inv);
    atomicAdd(o + 2, acc.z * inv);
    atomicAdd(o + 3, acc.w * inv);
}

extern "C" void kernel_launch(void* const* d_in, const int* in_sizes, int n_in,
                              void* d_out, int out_size, void* d_ws, size_t ws_size,
                              hipStream_t stream) {
    const float* in  = (const float*)d_in[0];
    const int*   len = (const int*)d_in[1];
    float*       out = (float*)d_out;

    const size_t need128 = (size_t)BB * 128 * DD * sizeof(float); // 8 MiB
    const size_t need64  = (size_t)BB * 64  * DD * sizeof(float); // 4 MiB

    if (d_ws != nullptr && ws_size >= need128) {
        float* ws = (float*)d_ws;
        avg_partial_kernel<128><<<(BB * 128) / WAVES, 256, 0, stream>>>(in, len, ws);
        avg_reduce_kernel<128><<<BB, 64 * RWAVES, 0, stream>>>(ws, len, out);
    } else if (d_ws != nullptr && ws_size >= need64) {
        float* ws = (float*)d_ws;
        avg_partial_kernel<64><<<(BB * 64) / WAVES, 256, 0, stream>>>(in, len, ws);
        avg_reduce_kernel<64><<<BB, 64 * RWAVES, 0, stream>>>(ws, len, out);
    } else {
        avg_zero_out_kernel<<<(BB * DD + 255) / 256, 256, 0, stream>>>(out);
        avg_atomic_kernel<<<BB * 64, 64, 0, stream>>>(in, len, out);
    }
}